// Round 10
// baseline (487.615 us; speedup 1.0000x reference)
//
#include <hip/hip_runtime.h>

// HashGridEncoding: N=2^20 points, 12 levels, T=2^19 entries/level, F=2.
//
// Round-10. Established:
//  - fine gather (levels 3-11): L2-request-throughput roofline, 205us
//    (rounds 7-9; sc0 A/B neutral; sort doesn't pay: rounds 2-4).
//  - backend: the LDS-transpose structure itself is the bottleneck. It runs
//    at 0.8-1.2 TB/s in EVERY variant (37% occ, 75% occ, hoisted loads),
//    while round-4's no-LDS straight-line finish kernel sustained 2.46 TB/s
//    incl. 380MB of scattered reads. Occupancy/latency models both failed;
//    the barrier+phase structure is what's slow.
// This round: finalize with NO LDS, NO barrier. Per thread: 9 hoisted nt
// ws loads -> 3 inline coarse encodes (overlap) -> 6 nt float4 stores to
// out[n*24..]. Per-thread 96B record => partial-line stores, measured 1.83x
// write inflation (round-4 finish) -- accepted: 224MB @ 2.4TB/s ~= 95us
// beats 144MB @ 1.1TB/s = 175us.
// Numerics identical (coarse fp32 exact, fine fp16-roundtrip) -> same absmax.

constexpr int NPTS     = 1 << 20;
constexpr int NLEVELS  = 12;
constexpr unsigned T     = 1u << 19;
constexpr unsigned TMASK = T - 1u;
constexpr unsigned P1 = 2654435761u;
constexpr unsigned P2 = 805459861u;

constexpr float WS_SCALE     = 16384.0f;          // 2^14, exact
constexpr float WS_INV_SCALE = 1.0f / 16384.0f;

typedef float    vfloat2 __attribute__((ext_vector_type(2)));
typedef float    vfloat4 __attribute__((ext_vector_type(4)));
typedef _Float16 vhalf2  __attribute__((ext_vector_type(2)));

// floor(16 * 1.38^l) for l=0..11 (verified in fp64)
__constant__ float c_res[NLEVELS] = {16.f, 22.f, 30.f, 42.f, 58.f, 80.f,
                                     110.f, 152.f, 210.f, 290.f, 400.f, 553.f};

// ---- L1-bypass gathers (sc0 = device-coherent: no L1 allocation, L2
//      replacement untouched). Neutral-vs-plain on fine levels (round-7
//      A/B); kept as the harness-proven fine-kernel path. ----

__device__ __forceinline__ void load4_x4_sc0(
    const vfloat4* a0, const vfloat4* a1, const vfloat4* a2, const vfloat4* a3,
    vfloat4& q0, vfloat4& q1, vfloat4& q2, vfloat4& q3)
{
    asm volatile(
        "global_load_dwordx4 %0, %4, off sc0\n\t"
        "global_load_dwordx4 %1, %5, off sc0\n\t"
        "global_load_dwordx4 %2, %6, off sc0\n\t"
        "global_load_dwordx4 %3, %7, off sc0\n\t"
        "s_waitcnt vmcnt(0)"
        : "=&v"(q0), "=&v"(q1), "=&v"(q2), "=&v"(q3)
        : "v"(a0), "v"(a1), "v"(a2), "v"(a3));
}

__device__ __forceinline__ void load8_x2_sc0(
    const vfloat2* a0, const vfloat2* a1, const vfloat2* a2, const vfloat2* a3,
    const vfloat2* a4, const vfloat2* a5, const vfloat2* a6, const vfloat2* a7,
    vfloat2& q0, vfloat2& q1, vfloat2& q2, vfloat2& q3,
    vfloat2& q4, vfloat2& q5, vfloat2& q6, vfloat2& q7)
{
    asm volatile(
        "global_load_dwordx2 %0, %8, off sc0\n\t"
        "global_load_dwordx2 %1, %9, off sc0\n\t"
        "global_load_dwordx2 %2, %10, off sc0\n\t"
        "global_load_dwordx2 %3, %11, off sc0\n\t"
        "global_load_dwordx2 %4, %12, off sc0\n\t"
        "global_load_dwordx2 %5, %13, off sc0\n\t"
        "global_load_dwordx2 %6, %14, off sc0\n\t"
        "global_load_dwordx2 %7, %15, off sc0\n\t"
        "s_waitcnt vmcnt(0)"
        : "=&v"(q0), "=&v"(q1), "=&v"(q2), "=&v"(q3),
          "=&v"(q4), "=&v"(q5), "=&v"(q6), "=&v"(q7)
        : "v"(a0), "v"(a1), "v"(a2), "v"(a3),
          "v"(a4), "v"(a5), "v"(a6), "v"(a7));
}

template <bool BYPASS>
__device__ __forceinline__ float2 encode_one_level(
    float px, float py, float pz, float r, const float2* __restrict__ tab)
{
    const float xs = px * r, ys = py * r, zs = pz * r;
    const float xf = floorf(xs), yf = floorf(ys), zf = floorf(zs);
    const float wx = xs - xf, wy = ys - yf, wz = zs - zf;
    const unsigned xi = (unsigned)xf, yi = (unsigned)yf, zi = (unsigned)zf;

    // Y hash component for the 4 (oy,oz) pairs; corner c = ox + 2*oy + 4*oz.
    unsigned Y[4];
#pragma unroll
    for (int j = 0; j < 4; ++j) {
        const unsigned oy = j & 1u, oz = (j >> 1) & 1u;
        Y[j] = ((yi + oy) * P1) ^ ((zi + oz) * P2);
    }

    float2 f[8];
    if ((xi & 1u) == 0u) {
        // even xi: corners (ox=0 -> h, ox=1 -> h^1) share one 16B-aligned pair
        unsigned h[4];
#pragma unroll
        for (int j = 0; j < 4; ++j) h[j] = (xi ^ Y[j]) & TMASK;

        vfloat4 q[4];
        if constexpr (BYPASS) {
            load4_x4_sc0(reinterpret_cast<const vfloat4*>(tab + (h[0] & ~1u)),
                         reinterpret_cast<const vfloat4*>(tab + (h[1] & ~1u)),
                         reinterpret_cast<const vfloat4*>(tab + (h[2] & ~1u)),
                         reinterpret_cast<const vfloat4*>(tab + (h[3] & ~1u)),
                         q[0], q[1], q[2], q[3]);
        } else {
#pragma unroll
            for (int j = 0; j < 4; ++j)
                q[j] = *reinterpret_cast<const vfloat4*>(tab + (h[j] & ~1u));
        }
#pragma unroll
        for (int j = 0; j < 4; ++j) {
            const bool hi = (h[j] & 1u) != 0u;   // entry h sits in high half?
            const float2 e_lo = make_float2(q[j].x, q[j].y);
            const float2 e_hi = make_float2(q[j].z, q[j].w);
            f[2 * j + 0] = hi ? e_hi : e_lo;     // ox=0 -> entry h
            f[2 * j + 1] = hi ? e_lo : e_hi;     // ox=1 -> entry h^1
        }
    } else {
        if constexpr (BYPASS) {
            const vfloat2* a[8];
#pragma unroll
            for (int j = 0; j < 4; ++j) {
                a[2 * j + 0] = reinterpret_cast<const vfloat2*>(
                    tab + ((xi ^ Y[j]) & TMASK));
                a[2 * j + 1] = reinterpret_cast<const vfloat2*>(
                    tab + (((xi + 1u) ^ Y[j]) & TMASK));
            }
            vfloat2 q[8];
            load8_x2_sc0(a[0], a[1], a[2], a[3], a[4], a[5], a[6], a[7],
                         q[0], q[1], q[2], q[3], q[4], q[5], q[6], q[7]);
#pragma unroll
            for (int c = 0; c < 8; ++c) f[c] = make_float2(q[c].x, q[c].y);
        } else {
#pragma unroll
            for (int j = 0; j < 4; ++j) {
                const unsigned h0 = (xi ^ Y[j]) & TMASK;
                const unsigned h1 = ((xi + 1u) ^ Y[j]) & TMASK;
                f[2 * j + 0] = tab[h0];
                f[2 * j + 1] = tab[h1];
            }
        }
    }

    // accumulation order identical to reference (c = 0..7) -> bit-stable
    float f0 = 0.f, f1 = 0.f;
#pragma unroll
    for (int c = 0; c < 8; ++c) {
        const unsigned ox = c & 1u, oy = (c >> 1) & 1u, oz = (c >> 2) & 1u;
        const float w = (ox ? wx : 1.f - wx) *
                        (oy ? wy : 1.f - wy) *
                        (oz ? wz : 1.f - wz);
        f0 += w * f[c].x;
        f1 += w * f[c].y;
    }
    return make_float2(f0, f1);
}

// Phase 1: FINE levels only. grid (NPTS/256, 9), level = 3 + blockIdx.y.
// Proven kernel (205us, L2-request-throughput roofline).
__global__ __launch_bounds__(256, 8)
void hashgrid_level_kernel(const float* __restrict__ x,
                           const float* __restrict__ tables,
                           _Float16* __restrict__ ws)
{
    const int n = blockIdx.x * 256 + threadIdx.x;
    const int l = 3 + blockIdx.y;

    const float px = x[3 * n + 0];
    const float py = x[3 * n + 1];
    const float pz = x[3 * n + 2];

    const float2* __restrict__ tab =
        reinterpret_cast<const float2*>(tables) + (size_t)l * T;

    const float2 f = encode_one_level<true>(px, py, pz, c_res[l], tab);
    vhalf2 h = {(_Float16)(f.x * WS_SCALE), (_Float16)(f.y * WS_SCALE)};
    __builtin_nontemporal_store(
        h, reinterpret_cast<vhalf2*>(ws) + ((size_t)l * NPTS + n));
}

// Phase 2: finalize v3 -- NO LDS, NO barrier (round-4 finish structure,
// the measured 2.46 TB/s pattern). Per thread:
//   (a) 9 hoisted nt ws loads (dword = one vhalf2; index l*NPTS+n)
//   (b) 3 coarse encodes while loads are in flight (fp32 exact)
//   (c) convert fine levels, (d) 6 nt float4 stores, out[n*24..n*24+23].
// Per-thread 96B record -> partial-line stores (1.83x write inflation,
// measured round 4) -- net win vs the 1.1 TB/s LDS transpose.
__global__ __launch_bounds__(256)
void hashgrid_finalize_kernel(const float* __restrict__ x,
                              const float* __restrict__ tables,
                              const _Float16* __restrict__ ws,
                              float* __restrict__ out)
{
    const int n = blockIdx.x * 256 + threadIdx.x;

    // (a) all 9 fine ws loads issued up-front (coalesced 1KB/wave per level)
    const unsigned* __restrict__ wsd = reinterpret_cast<const unsigned*>(ws);
    unsigned wv[9];
#pragma unroll
    for (int l = 3; l < NLEVELS; ++l)
        wv[l - 3] = __builtin_nontemporal_load(wsd + ((size_t)l * NPTS + n));

    float o[2 * NLEVELS];

    // (b) coarse levels 0-2 inline (tables <1MB total -> L2-resident)
    const float px = x[3 * n + 0];
    const float py = x[3 * n + 1];
    const float pz = x[3 * n + 2];
#pragma unroll
    for (int l = 0; l < 3; ++l) {
        const float2* __restrict__ tab =
            reinterpret_cast<const float2*>(tables) + (size_t)l * T;
        const float2 f = encode_one_level<false>(px, py, pz, c_res[l], tab);
        o[2 * l + 0] = f.x;
        o[2 * l + 1] = f.y;
    }

    // (c) fine levels from the in-flight loads
#pragma unroll
    for (int l = 3; l < NLEVELS; ++l) {
        const vhalf2 h = __builtin_bit_cast(vhalf2, wv[l - 3]);
        o[2 * l + 0] = (float)h.x * WS_INV_SCALE;
        o[2 * l + 1] = (float)h.y * WS_INV_SCALE;
    }

    // (d) direct stores: 6 x float4, 96B/thread, wave covers 6KB contiguous
    float* __restrict__ op = out + (size_t)n * 24;
#pragma unroll
    for (int i = 0; i < 6; ++i) {
        const vfloat4 v = {o[4 * i + 0], o[4 * i + 1],
                           o[4 * i + 2], o[4 * i + 3]};
        __builtin_nontemporal_store(v, reinterpret_cast<vfloat4*>(op) + i);
    }
}

// Fallback (ws too small): point-major fused kernel, direct (N,24) writes.
__global__ __launch_bounds__(256, 4)
void hashgrid_fused_kernel(const float* __restrict__ x,
                           const float* __restrict__ tables,
                           float* __restrict__ out)
{
    const int n = blockIdx.x * 256 + threadIdx.x;
    const float px = x[3 * n + 0];
    const float py = x[3 * n + 1];
    const float pz = x[3 * n + 2];

    float o[2 * NLEVELS];
#pragma unroll
    for (int l = 0; l < NLEVELS; ++l) {
        const float2* __restrict__ tab =
            reinterpret_cast<const float2*>(tables) + (size_t)l * T;
        const float2 f = encode_one_level<false>(px, py, pz, c_res[l], tab);
        o[2 * l + 0] = f.x;
        o[2 * l + 1] = f.y;
    }
    float4* __restrict__ op = reinterpret_cast<float4*>(out + (size_t)n * 24);
#pragma unroll
    for (int i = 0; i < 6; ++i)
        op[i] = make_float4(o[4*i+0], o[4*i+1], o[4*i+2], o[4*i+3]);
}

extern "C" void kernel_launch(void* const* d_in, const int* in_sizes, int n_in,
                              void* d_out, int out_size, void* d_ws, size_t ws_size,
                              hipStream_t stream)
{
    const float* x      = reinterpret_cast<const float*>(d_in[0]);   // (N,3)
    const float* tables = reinterpret_cast<const float*>(d_in[1]);   // (12,T,2)
    float* out          = reinterpret_cast<float*>(d_out);           // (N,24)

    const size_t ws_needed = (size_t)NLEVELS * NPTS * 2 * sizeof(_Float16); // ~50MB
    if (ws_size >= ws_needed) {
        _Float16* ws = reinterpret_cast<_Float16*>(d_ws);
        // fine levels 3-11 (L2-request-bound roofline, proven 205us)
        hashgrid_level_kernel
            <<<dim3(NPTS / 256, 9), 256, 0, stream>>>(x, tables, ws);
        // no-LDS finalize: ws + coarse -> direct register stores
        hashgrid_finalize_kernel
            <<<NPTS / 256, 256, 0, stream>>>(x, tables, ws, out);
    } else {
        hashgrid_fused_kernel<<<NPTS / 256, 256, 0, stream>>>(x, tables, out);
    }
}

// Round 11
// 381.131 us; speedup vs baseline: 1.2794x; 1.2794x over previous
//
#include <hip/hip_runtime.h>

// HashGridEncoding: N=2^20 points, 12 levels, T=2^19 entries/level, F=2.
//
// FINAL configuration (= round-8, best measured 380.6us). Session accounting
// (closed in round 10, fits all 10 rounds within noise):
//   - fine gather (levels 3-11): 205us at ~90% of the L2 request-throughput
//     ceiling (~2.2 cyc/CU per divergent request; 384 req/wave-level).
//     sc0 L1-bypass A/B = neutral (request-count-bound, not bytes);
//     request count is provably minimal for this hash (odd-xi corners span
//     two aligned pairs); spatial sort saves ~87us of requests but costs
//     ~130us of prelude (measured rounds 2-4) -> net loss.
//   - finalize: LDS transpose (~32us pure) + inline coarse levels 0-2
//     (~43us, TA-rate on L1/L2-resident tables) = ~75us. No-LDS direct
//     stores = 182us (write inflation, round 10); occupancy/hoisting
//     variants neutral (rounds 9/10).
//   - remaining ~100us/iteration is harness reset overhead (out memset,
//     ws re-poison, restore dispatches), outside kernel control.

constexpr int NPTS     = 1 << 20;
constexpr int NLEVELS  = 12;
constexpr unsigned T     = 1u << 19;
constexpr unsigned TMASK = T - 1u;
constexpr unsigned P1 = 2654435761u;
constexpr unsigned P2 = 805459861u;

constexpr float WS_SCALE     = 16384.0f;          // 2^14, exact
constexpr float WS_INV_SCALE = 1.0f / 16384.0f;

typedef float    vfloat2 __attribute__((ext_vector_type(2)));
typedef float    vfloat4 __attribute__((ext_vector_type(4)));
typedef _Float16 vhalf2  __attribute__((ext_vector_type(2)));

// floor(16 * 1.38^l) for l=0..11 (verified in fp64)
__constant__ float c_res[NLEVELS] = {16.f, 22.f, 30.f, 42.f, 58.f, 80.f,
                                     110.f, 152.f, 210.f, 290.f, 400.f, 553.f};

// ---- L1-bypass gathers (sc0 = device-coherent: no L1 allocation, L2
//      replacement untouched). Neutral-vs-plain on fine levels (round-7
//      A/B); kept as the harness-proven fine-kernel path. ----

__device__ __forceinline__ void load4_x4_sc0(
    const vfloat4* a0, const vfloat4* a1, const vfloat4* a2, const vfloat4* a3,
    vfloat4& q0, vfloat4& q1, vfloat4& q2, vfloat4& q3)
{
    asm volatile(
        "global_load_dwordx4 %0, %4, off sc0\n\t"
        "global_load_dwordx4 %1, %5, off sc0\n\t"
        "global_load_dwordx4 %2, %6, off sc0\n\t"
        "global_load_dwordx4 %3, %7, off sc0\n\t"
        "s_waitcnt vmcnt(0)"
        : "=&v"(q0), "=&v"(q1), "=&v"(q2), "=&v"(q3)
        : "v"(a0), "v"(a1), "v"(a2), "v"(a3));
}

__device__ __forceinline__ void load8_x2_sc0(
    const vfloat2* a0, const vfloat2* a1, const vfloat2* a2, const vfloat2* a3,
    const vfloat2* a4, const vfloat2* a5, const vfloat2* a6, const vfloat2* a7,
    vfloat2& q0, vfloat2& q1, vfloat2& q2, vfloat2& q3,
    vfloat2& q4, vfloat2& q5, vfloat2& q6, vfloat2& q7)
{
    asm volatile(
        "global_load_dwordx2 %0, %8, off sc0\n\t"
        "global_load_dwordx2 %1, %9, off sc0\n\t"
        "global_load_dwordx2 %2, %10, off sc0\n\t"
        "global_load_dwordx2 %3, %11, off sc0\n\t"
        "global_load_dwordx2 %4, %12, off sc0\n\t"
        "global_load_dwordx2 %5, %13, off sc0\n\t"
        "global_load_dwordx2 %6, %14, off sc0\n\t"
        "global_load_dwordx2 %7, %15, off sc0\n\t"
        "s_waitcnt vmcnt(0)"
        : "=&v"(q0), "=&v"(q1), "=&v"(q2), "=&v"(q3),
          "=&v"(q4), "=&v"(q5), "=&v"(q6), "=&v"(q7)
        : "v"(a0), "v"(a1), "v"(a2), "v"(a3),
          "v"(a4), "v"(a5), "v"(a6), "v"(a7));
}

template <bool BYPASS>
__device__ __forceinline__ float2 encode_one_level(
    float px, float py, float pz, float r, const float2* __restrict__ tab)
{
    const float xs = px * r, ys = py * r, zs = pz * r;
    const float xf = floorf(xs), yf = floorf(ys), zf = floorf(zs);
    const float wx = xs - xf, wy = ys - yf, wz = zs - zf;
    const unsigned xi = (unsigned)xf, yi = (unsigned)yf, zi = (unsigned)zf;

    // Y hash component for the 4 (oy,oz) pairs; corner c = ox + 2*oy + 4*oz.
    unsigned Y[4];
#pragma unroll
    for (int j = 0; j < 4; ++j) {
        const unsigned oy = j & 1u, oz = (j >> 1) & 1u;
        Y[j] = ((yi + oy) * P1) ^ ((zi + oz) * P2);
    }

    float2 f[8];
    if ((xi & 1u) == 0u) {
        // even xi: corners (ox=0 -> h, ox=1 -> h^1) share one 16B-aligned pair
        unsigned h[4];
#pragma unroll
        for (int j = 0; j < 4; ++j) h[j] = (xi ^ Y[j]) & TMASK;

        vfloat4 q[4];
        if constexpr (BYPASS) {
            load4_x4_sc0(reinterpret_cast<const vfloat4*>(tab + (h[0] & ~1u)),
                         reinterpret_cast<const vfloat4*>(tab + (h[1] & ~1u)),
                         reinterpret_cast<const vfloat4*>(tab + (h[2] & ~1u)),
                         reinterpret_cast<const vfloat4*>(tab + (h[3] & ~1u)),
                         q[0], q[1], q[2], q[3]);
        } else {
#pragma unroll
            for (int j = 0; j < 4; ++j)
                q[j] = *reinterpret_cast<const vfloat4*>(tab + (h[j] & ~1u));
        }
#pragma unroll
        for (int j = 0; j < 4; ++j) {
            const bool hi = (h[j] & 1u) != 0u;   // entry h sits in high half?
            const float2 e_lo = make_float2(q[j].x, q[j].y);
            const float2 e_hi = make_float2(q[j].z, q[j].w);
            f[2 * j + 0] = hi ? e_hi : e_lo;     // ox=0 -> entry h
            f[2 * j + 1] = hi ? e_lo : e_hi;     // ox=1 -> entry h^1
        }
    } else {
        if constexpr (BYPASS) {
            const vfloat2* a[8];
#pragma unroll
            for (int j = 0; j < 4; ++j) {
                a[2 * j + 0] = reinterpret_cast<const vfloat2*>(
                    tab + ((xi ^ Y[j]) & TMASK));
                a[2 * j + 1] = reinterpret_cast<const vfloat2*>(
                    tab + (((xi + 1u) ^ Y[j]) & TMASK));
            }
            vfloat2 q[8];
            load8_x2_sc0(a[0], a[1], a[2], a[3], a[4], a[5], a[6], a[7],
                         q[0], q[1], q[2], q[3], q[4], q[5], q[6], q[7]);
#pragma unroll
            for (int c = 0; c < 8; ++c) f[c] = make_float2(q[c].x, q[c].y);
        } else {
#pragma unroll
            for (int j = 0; j < 4; ++j) {
                const unsigned h0 = (xi ^ Y[j]) & TMASK;
                const unsigned h1 = ((xi + 1u) ^ Y[j]) & TMASK;
                f[2 * j + 0] = tab[h0];
                f[2 * j + 1] = tab[h1];
            }
        }
    }

    // accumulation order identical to reference (c = 0..7) -> bit-stable
    float f0 = 0.f, f1 = 0.f;
#pragma unroll
    for (int c = 0; c < 8; ++c) {
        const unsigned ox = c & 1u, oy = (c >> 1) & 1u, oz = (c >> 2) & 1u;
        const float w = (ox ? wx : 1.f - wx) *
                        (oy ? wy : 1.f - wy) *
                        (oz ? wz : 1.f - wz);
        f0 += w * f[c].x;
        f1 += w * f[c].y;
    }
    return make_float2(f0, f1);
}

// Phase 1: FINE levels only. grid (NPTS/256, 9), level = 3 + blockIdx.y.
// Proven kernel (205us, ~90% of the L2 request-throughput ceiling).
__global__ __launch_bounds__(256, 8)
void hashgrid_level_kernel(const float* __restrict__ x,
                           const float* __restrict__ tables,
                           _Float16* __restrict__ ws)
{
    const int n = blockIdx.x * 256 + threadIdx.x;
    const int l = 3 + blockIdx.y;

    const float px = x[3 * n + 0];
    const float py = x[3 * n + 1];
    const float pz = x[3 * n + 2];

    const float2* __restrict__ tab =
        reinterpret_cast<const float2*>(tables) + (size_t)l * T;

    const float2 f = encode_one_level<true>(px, py, pz, c_res[l], tab);
    vhalf2 h = {(_Float16)(f.x * WS_SCALE), (_Float16)(f.y * WS_SCALE)};
    __builtin_nontemporal_store(
        h, reinterpret_cast<vhalf2*>(ws) + ((size_t)l * NPTS + n));
}

// Phase 2: finalize = transpose (levels 3-11 from ws, round-0 proven code)
// + inline coarse levels 0-2 (plain loads, tables L1/L2-resident, fp32
// straight to LDS -- no fp16 quantization for these levels).
// 512 points/block; thread t handles rows t and t+256 (LDS stride 25 odd ->
// conflict-free). Global writes are lane-contiguous full-line float4s.
__global__ __launch_bounds__(256)
void hashgrid_finalize_kernel(const float* __restrict__ x,
                              const float* __restrict__ tables,
                              const _Float16* __restrict__ ws,
                              float* __restrict__ out)
{
    __shared__ float lds[512 * 25];
    const int t = threadIdx.x;
    const int base = blockIdx.x * 512;

    // fine levels 3-11 from ws (byte-identical to round-0 transpose reads)
#pragma unroll
    for (int l = 3; l < NLEVELS; ++l) {
#pragma unroll
        for (int k = 0; k < 2; ++k) {
            const int p = t + 256 * k;
            const vhalf2 h = __builtin_nontemporal_load(
                reinterpret_cast<const vhalf2*>(ws) + ((size_t)l * NPTS + base + p));
            lds[p * 25 + 2 * l + 0] = (float)h.x * WS_INV_SCALE;
            lds[p * 25 + 2 * l + 1] = (float)h.y * WS_INV_SCALE;
        }
    }

    // coarse levels 0-2 computed inline (gathers hit L1/L2)
#pragma unroll
    for (int k = 0; k < 2; ++k) {
        const int p = t + 256 * k;
        const int n = base + p;
        const float px = x[3 * n + 0];
        const float py = x[3 * n + 1];
        const float pz = x[3 * n + 2];
#pragma unroll
        for (int l = 0; l < 3; ++l) {
            const float2* __restrict__ tab =
                reinterpret_cast<const float2*>(tables) + (size_t)l * T;
            const float2 f = encode_one_level<false>(px, py, pz, c_res[l], tab);
            lds[p * 25 + 2 * l + 0] = f.x;   // stride 25 odd -> conflict-free
            lds[p * 25 + 2 * l + 1] = f.y;
        }
    }
    __syncthreads();

    // Block's output region: 512*24 floats = 3072 float4, lane-contiguous.
    float* __restrict__ ob = out + (size_t)base * 24;
#pragma unroll
    for (int i = 0; i < 12; ++i) {
        const int j  = i * 256 + t;   // float4 index within block
        const int f0 = 4 * j;         // flat float offset
        const int p  = f0 / 24;       // local point
        const int c  = f0 % 24;       // component (multiple of 4)
        vfloat4 v = {lds[p * 25 + c + 0], lds[p * 25 + c + 1],
                     lds[p * 25 + c + 2], lds[p * 25 + c + 3]};
        __builtin_nontemporal_store(v, reinterpret_cast<vfloat4*>(ob + f0));
    }
}

// Fallback (ws too small): point-major fused kernel, direct (N,24) writes.
__global__ __launch_bounds__(256, 4)
void hashgrid_fused_kernel(const float* __restrict__ x,
                           const float* __restrict__ tables,
                           float* __restrict__ out)
{
    const int n = blockIdx.x * 256 + threadIdx.x;
    const float px = x[3 * n + 0];
    const float py = x[3 * n + 1];
    const float pz = x[3 * n + 2];

    float o[2 * NLEVELS];
#pragma unroll
    for (int l = 0; l < NLEVELS; ++l) {
        const float2* __restrict__ tab =
            reinterpret_cast<const float2*>(tables) + (size_t)l * T;
        const float2 f = encode_one_level<false>(px, py, pz, c_res[l], tab);
        o[2 * l + 0] = f.x;
        o[2 * l + 1] = f.y;
    }
    float4* __restrict__ op = reinterpret_cast<float4*>(out + (size_t)n * 24);
#pragma unroll
    for (int i = 0; i < 6; ++i)
        op[i] = make_float4(o[4*i+0], o[4*i+1], o[4*i+2], o[4*i+3]);
}

extern "C" void kernel_launch(void* const* d_in, const int* in_sizes, int n_in,
                              void* d_out, int out_size, void* d_ws, size_t ws_size,
                              hipStream_t stream)
{
    const float* x      = reinterpret_cast<const float*>(d_in[0]);   // (N,3)
    const float* tables = reinterpret_cast<const float*>(d_in[1]);   // (12,T,2)
    float* out          = reinterpret_cast<float*>(d_out);           // (N,24)

    const size_t ws_needed = (size_t)NLEVELS * NPTS * 2 * sizeof(_Float16); // ~50MB
    if (ws_size >= ws_needed) {
        _Float16* ws = reinterpret_cast<_Float16*>(d_ws);
        // fine levels 3-11 (L2-request-bound roofline, proven 205us)
        hashgrid_level_kernel
            <<<dim3(NPTS / 256, 9), 256, 0, stream>>>(x, tables, ws);
        // transpose + inline coarse levels 0-2 (proven 380.6us total)
        hashgrid_finalize_kernel
            <<<NPTS / 512, 256, 0, stream>>>(x, tables, ws, out);
    } else {
        hashgrid_fused_kernel<<<NPTS / 256, 256, 0, stream>>>(x, tables, out);
    }
}